// Round 1
// baseline (536.363 us; speedup 1.0000x reference)
//
#include <hip/hip_runtime.h>
#include <math.h>

// CNN_tcn: B=256 samples, one block per sample (grid 256 = #CUs), one thread
// per row a (block 512). All per-sample LayerNorms are block-local reductions.
// The dilated (1,3),dil=2 conv is 1-D along d -> rolling 5-wide register
// window per thread. x1/x2/x3 are never materialized: the linear tail
// (concat-LN -> cw 1x1 -> c2w (1,D)) is folded into 16 persistent per-thread
// accumulators t16a[o] via E_i[o,cc,d] = sum_co c2w[o,co,d]*cw[co,i*4+cc],
// with the concat-LN affine applied afterwards: t = r*(T_raw - m*K[o]).
// Workspace: ONE [B][D][A] float4 buffer (128 MiB), updated in place
// (base2 -> base3); each thread only ever touches its own (b,a) column.

#define EPS_LN 1e-5f
typedef float4 f4;

__device__ __forceinline__ float gelu_f(float v) {
    return 0.5f * v * (1.0f + erff(v * 0.70710678118654752440f));
}

// y[o] = dilated conv taps: a = base[d-2], c = base[d], e = base[d+2]
// wd layout (4,4,1,3): [o][cin][k] flat o*12 + cin*3 + k
__device__ __forceinline__ void conv4(const f4 a, const f4 c, const f4 e,
                                      const float* __restrict__ wd, float y[4]) {
#pragma unroll
    for (int o = 0; o < 4; ++o) {
        const float* wv = wd + o * 12;
        y[o] = fmaf(a.x, wv[0], fmaf(c.x, wv[1], fmaf(e.x, wv[2],
               fmaf(a.y, wv[3], fmaf(c.y, wv[4], fmaf(e.y, wv[5],
               fmaf(a.z, wv[6], fmaf(c.z, wv[7], fmaf(e.z, wv[8],
               fmaf(a.w, wv[9], fmaf(c.w, wv[10], e.w * wv[11])))))))))));
    }
}

__device__ __forceinline__ void block_red2(float& a, float& b2, float* red,
                                           float* bc, int tid) {
#pragma unroll
    for (int off = 32; off > 0; off >>= 1) {
        a  += __shfl_down(a,  off, 64);
        b2 += __shfl_down(b2, off, 64);
    }
    if ((tid & 63) == 0) { red[tid >> 6] = a; red[8 + (tid >> 6)] = b2; }
    __syncthreads();
    if (tid == 0) {
        float x = 0.f, y = 0.f;
#pragma unroll
        for (int i = 0; i < 8; ++i) { x += red[i]; y += red[8 + i]; }
        bc[0] = x; bc[1] = y;
    }
    __syncthreads();
    a = bc[0]; b2 = bc[1];
}

__global__ __launch_bounds__(512)
void tcn_fused(const float* __restrict__ sIn, const float* __restrict__ wIn,
               const float* __restrict__ w1d, const float* __restrict__ w1p,
               const float* __restrict__ w2d, const float* __restrict__ w2p,
               const float* __restrict__ w3d, const float* __restrict__ w3p,
               const float* __restrict__ cw,  const float* __restrict__ c2w,
               const float* __restrict__ c3w, float* __restrict__ out,
               f4* __restrict__ baseT) {
    const int b   = blockIdx.x;
    const int tid = threadIdx.x;            // == row a

    __shared__ float red[16];
    __shared__ float bc[2];
    __shared__ float Klds[16];

    // K[o] = sum_{co,d} c2w[o,co,d] * (sum_{j<12} cw[co*12+j])
    if (tid < 16) {
        float k = 0.f;
        for (int co = 0; co < 4; ++co) {
            float cs = 0.f;
            for (int j = 0; j < 12; ++j) cs += cw[co * 12 + j];
            const float* p = c2w + tid * 256 + co * 64;
            float t = 0.f;
            for (int d = 0; d < 64; ++d) t += p[d];
            k = fmaf(cs, t, k);
        }
        Klds[tid] = k;
    }

    const f4* s4 = (const f4*)sIn;
    const size_t srow = ((size_t)b * 512 + tid) * 64;        // s: [b][a][d] f4
    const size_t brow = (size_t)b * (64 * 512) + tid;        // base: [b][d][a] f4
    const f4 z4 = make_float4(0.f, 0.f, 0.f, 0.f);
    const float NY = 4.f * 512.f * 64.f;                     // 131072

    // ---------- Phase A: stats of y1 = conv(s) ----------
    float s1 = 0.f, s2 = 0.f;
    {
        f4 wA = z4, wB = z4, wC = s4[srow], wD = s4[srow + 1], wE;
        for (int d = 0; d < 64; ++d) {
            wE = (d + 2 < 64) ? s4[srow + d + 2] : z4;
            float y[4]; conv4(wA, wC, wE, w1d, y);
#pragma unroll
            for (int o = 0; o < 4; ++o) { s1 += y[o]; s2 = fmaf(y[o], y[o], s2); }
            wA = wB; wB = wC; wC = wD; wD = wE;
        }
    }
    block_red2(s1, s2, red, bc, tid);
    float m1 = s1 / NY;
    float r1 = rsqrtf(s2 / NY - m1 * m1 + EPS_LN);

    float t16a[16];
#pragma unroll
    for (int o = 0; o < 16; ++o) t16a[o] = 0.f;
    float cs1 = 0.f, cs2 = 0.f;

    // ---------- Phase B: x1, base2 = s+x1 (store), stats of y2 ----------
    float q1 = 0.f, q2 = 0.f;
    {
        f4 wA = z4, wB = z4, wC = s4[srow], wD = s4[srow + 1], wE;
        f4 bA = z4, bB = z4, bC = z4, bD = z4, bE;
        for (int d = 0; d < 66; ++d) {
            if (d < 64) {
                wE = (d + 2 < 64) ? s4[srow + d + 2] : z4;
                float y[4]; conv4(wA, wC, wE, w1d, y);
#pragma unroll
                for (int o = 0; o < 4; ++o) y[o] = (y[o] - m1) * r1;
                float g[4];
#pragma unroll
                for (int o = 0; o < 4; ++o) {
                    float zz = fmaf(y[0], w1p[o*4+0], fmaf(y[1], w1p[o*4+1],
                               fmaf(y[2], w1p[o*4+2], y[3] * w1p[o*4+3])));
                    g[o] = gelu_f(zz);
                }
#pragma unroll
                for (int o = 0; o < 4; ++o) { cs1 += g[o]; cs2 = fmaf(g[o], g[o], cs2); }
                float u[4];
#pragma unroll
                for (int co = 0; co < 4; ++co)
                    u[co] = fmaf(g[0], cw[co*12+0], fmaf(g[1], cw[co*12+1],
                            fmaf(g[2], cw[co*12+2], g[3] * cw[co*12+3])));
#pragma unroll
                for (int o = 0; o < 16; ++o) {
                    const float* p = c2w + o * 256 + d;
                    t16a[o] = fmaf(u[0], p[0], fmaf(u[1], p[64],
                              fmaf(u[2], p[128], fmaf(u[3], p[192], t16a[o]))));
                }
                f4 nb;
                nb.x = wC.x + g[0]; nb.y = wC.y + g[1];
                nb.z = wC.z + g[2]; nb.w = wC.w + g[3];
                baseT[brow + (size_t)d * 512] = nb;
                bE = nb;
                wA = wB; wB = wC; wC = wD; wD = wE;
            } else bE = z4;
            if (d >= 2) {                      // y2 at e=d-2: taps d-4, d-2, d
                float y2[4]; conv4(bA, bC, bE, w2d, y2);
#pragma unroll
                for (int o = 0; o < 4; ++o) { q1 += y2[o]; q2 = fmaf(y2[o], y2[o], q2); }
            }
            bA = bB; bB = bC; bC = bD; bD = bE;
        }
    }
    block_red2(q1, q2, red, bc, tid);
    float m2s = q1 / NY;
    float r2s = rsqrtf(q2 / NY - m2s * m2s + EPS_LN);

    // ---------- Phase C: x2, base3 = base2+x2 (in-place), stats of y3 ----------
    float q31 = 0.f, q32 = 0.f;
    {
        f4 gA = z4, gB = z4, gC = z4, gD = z4, gE;
        f4 hA = z4, hB = z4, hC = z4, hD = z4, hE;
        for (int t = 0; t < 68; ++t) {
            gE = (t < 64) ? baseT[brow + (size_t)t * 512] : z4;
            if (t >= 2 && t < 66) {
                const int e = t - 2;
                float y[4]; conv4(gA, gC, gE, w2d, y);
#pragma unroll
                for (int o = 0; o < 4; ++o) y[o] = (y[o] - m2s) * r2s;
                float g[4];
#pragma unroll
                for (int o = 0; o < 4; ++o) {
                    float zz = fmaf(y[0], w2p[o*4+0], fmaf(y[1], w2p[o*4+1],
                               fmaf(y[2], w2p[o*4+2], y[3] * w2p[o*4+3])));
                    g[o] = gelu_f(zz);
                }
#pragma unroll
                for (int o = 0; o < 4; ++o) { cs1 += g[o]; cs2 = fmaf(g[o], g[o], cs2); }
                float u[4];
#pragma unroll
                for (int co = 0; co < 4; ++co)
                    u[co] = fmaf(g[0], cw[co*12+4], fmaf(g[1], cw[co*12+5],
                            fmaf(g[2], cw[co*12+6], g[3] * cw[co*12+7])));
#pragma unroll
                for (int o = 0; o < 16; ++o) {
                    const float* p = c2w + o * 256 + e;
                    t16a[o] = fmaf(u[0], p[0], fmaf(u[1], p[64],
                              fmaf(u[2], p[128], fmaf(u[3], p[192], t16a[o]))));
                }
                f4 nb;
                nb.x = gC.x + g[0]; nb.y = gC.y + g[1];
                nb.z = gC.z + g[2]; nb.w = gC.w + g[3];
                baseT[brow + (size_t)e * 512] = nb;   // in-place: e < t already read
                hE = nb;
            } else hE = z4;
            if (t >= 4) {                      // y3 at f=t-4: taps t-6, t-4, t-2
                float y3[4]; conv4(hA, hC, hE, w3d, y3);
#pragma unroll
                for (int o = 0; o < 4; ++o) { q31 += y3[o]; q32 = fmaf(y3[o], y3[o], q32); }
            }
            gA = gB; gB = gC; gC = gD; gD = gE;
            hA = hB; hB = hC; hC = hD; hD = hE;
        }
    }
    block_red2(q31, q32, red, bc, tid);
    float m3s = q31 / NY;
    float r3s = rsqrtf(q32 / NY - m3s * m3s + EPS_LN);

    // ---------- Phase D: x3 (reload base3) ----------
    {
        f4 wA = z4, wB = z4, wC = baseT[brow], wD = baseT[brow + 512], wE;
        for (int d = 0; d < 64; ++d) {
            wE = (d + 2 < 64) ? baseT[brow + (size_t)(d + 2) * 512] : z4;
            float y[4]; conv4(wA, wC, wE, w3d, y);
#pragma unroll
            for (int o = 0; o < 4; ++o) y[o] = (y[o] - m3s) * r3s;
            float g[4];
#pragma unroll
            for (int o = 0; o < 4; ++o) {
                float zz = fmaf(y[0], w3p[o*4+0], fmaf(y[1], w3p[o*4+1],
                           fmaf(y[2], w3p[o*4+2], y[3] * w3p[o*4+3])));
                g[o] = gelu_f(zz);
            }
#pragma unroll
            for (int o = 0; o < 4; ++o) { cs1 += g[o]; cs2 = fmaf(g[o], g[o], cs2); }
            float u[4];
#pragma unroll
            for (int co = 0; co < 4; ++co)
                u[co] = fmaf(g[0], cw[co*12+8], fmaf(g[1], cw[co*12+9],
                        fmaf(g[2], cw[co*12+10], g[3] * cw[co*12+11])));
#pragma unroll
            for (int o = 0; o < 16; ++o) {
                const float* p = c2w + o * 256 + d;
                t16a[o] = fmaf(u[0], p[0], fmaf(u[1], p[64],
                          fmaf(u[2], p[128], fmaf(u[3], p[192], t16a[o]))));
            }
            wA = wB; wB = wC; wC = wD; wD = wE;
        }
    }

    // ---------- concat LN stats over [12,A,D] ----------
    block_red2(cs1, cs2, red, bc, tid);
    const float NC = 12.f * 512.f * 64.f;                    // 393216
    float mcat = cs1 / NC;
    float rcat = rsqrtf(cs2 / NC - mcat * mcat + EPS_LN);

    // t16 values for this row; LN over [16, A]
    float tv[16];
    float p1 = 0.f, p2 = 0.f;
#pragma unroll
    for (int o = 0; o < 16; ++o) {
        float v = rcat * (t16a[o] - mcat * Klds[o]);
        tv[o] = v; p1 += v; p2 = fmaf(v, v, p2);
    }
    block_red2(p1, p2, red, bc, tid);
    const float N16 = 16.f * 512.f;                          // 8192
    float m16 = p1 / N16;
    float r16 = rsqrtf(p2 / N16 - m16 * m16 + EPS_LN);

    // c3w over 17 channels (16 normalized + raw w), then LN over A
    float v = wIn[(size_t)b * 512 + tid] * c3w[16];
#pragma unroll
    for (int o = 0; o < 16; ++o) v = fmaf((tv[o] - m16) * r16, c3w[o], v);
    float f1 = v, f2 = v * v;
    block_red2(f1, f2, red, bc, tid);
    float mA = f1 / 512.f;
    float rA = rsqrtf(f2 / 512.f - mA * mA + EPS_LN);

    out[(size_t)b * 512 + tid] = (v - mA) * rA;
}

extern "C" void kernel_launch(void* const* d_in, const int* in_sizes, int n_in,
                              void* d_out, int out_size, void* d_ws, size_t ws_size,
                              hipStream_t stream) {
    const float* s   = (const float*)d_in[0];
    const float* w   = (const float*)d_in[1];
    const float* w1d = (const float*)d_in[2];
    const float* w1p = (const float*)d_in[3];
    const float* w2d = (const float*)d_in[4];
    const float* w2p = (const float*)d_in[5];
    const float* w3d = (const float*)d_in[6];
    const float* w3p = (const float*)d_in[7];
    const float* cw  = (const float*)d_in[8];
    const float* c2w = (const float*)d_in[9];
    const float* c3w = (const float*)d_in[10];
    tcn_fused<<<dim3(256), dim3(512), 0, stream>>>(
        s, w, w1d, w1p, w2d, w2p, w3d, w3p, cw, c2w, c3w,
        (float*)d_out, (f4*)d_ws);
}